// Round 12
// baseline (217.099 us; speedup 1.0000x reference)
//
#include <hip/hip_runtime.h>
#include <hip/hip_bf16.h>
#include <stdint.h>

#define B_ 2
#define S_ 2048
#define D_ 1024
#define H_ 16
#define HD_ 64
#define KJL 32
#define N3 3072
#define N2 2048

typedef __attribute__((ext_vector_type(8))) __bf16 bf16x8;
typedef __attribute__((ext_vector_type(4))) float floatx4;
typedef __attribute__((ext_vector_type(4))) short short4v;
typedef __attribute__((ext_vector_type(2))) unsigned int uint2v;

__device__ __forceinline__ unsigned short f2b(float x) {
  union { float f; unsigned u; } v; v.f = x;
  unsigned r = v.u + 0x7fffu + ((v.u >> 16) & 1u);
  return (unsigned short)(r >> 16);
}

// pack two floats to packed bf16 (round via +0x8000): hi<<16 | lo
__device__ __forceinline__ unsigned int pkbf(float lo, float hi) {
  union { float f; unsigned u; } a, b;
  a.f = lo; b.f = hi;
  return __builtin_amdgcn_perm(b.u + 0x8000u, a.u + 0x8000u, 0x07060302u);
}

__device__ __forceinline__ void async16(const void* g, void* l) {
  __builtin_amdgcn_global_load_lds((__attribute__((address_space(1))) void*)(g),
                                   (__attribute__((address_space(3))) void*)(l),
                                   16, 0, 0);
}

// ---------------- fused prep: cvt4 | tcvt(V cols) | tcvt(W_proj) | wjl ----------------
__global__ __launch_bounds__(256)
void prep_kernel(const float* __restrict__ hidden, unsigned short* __restrict__ hB,
                 const float* __restrict__ W_attn, const float* __restrict__ b_attn,
                 const float* __restrict__ Sp, const float* __restrict__ W_proj,
                 unsigned short* __restrict__ Bt2, unsigned short* __restrict__ WpT,
                 float* __restrict__ bias2) {
  __shared__ float shmem[2048];
  const int bid = blockIdx.x;
  const int tid = threadIdx.x;

  if (bid < 512) {                      // ---- cvt4: hidden -> hB ----
    const int n4 = (B_ * S_ * D_) / 4;
    int i = bid * 256 + tid;
    for (; i < n4; i += 512 * 256) {
      float4 v = *(const float4*)(hidden + 4 * (size_t)i);
      short4v o = {(short)f2b(v.x), (short)f2b(v.y), (short)f2b(v.z), (short)f2b(v.w)};
      *(short4v*)(hB + 4 * (size_t)i) = o;
    }
  } else if (bid < 2560) {              // ---- tcvt: 32x32 transpose-convert tiles ----
    const float* in;
    unsigned short* out;
    int Cs, local;
    if (bid < 1536) { local = bid - 512;  in = W_attn + 2048; out = Bt2 + 1024 * 1024; Cs = N3; }
    else            { local = bid - 1536; in = W_proj;        out = WpT;               Cs = D_; }
    float (*t)[33] = (float(*)[33])shmem;
    int c0 = (local & 31) * 32, r0 = (local >> 5) * 32;
    int tx = tid & 31, ty = tid >> 5;
    for (int j = 0; j < 32; j += 8)
      t[ty + j][tx] = in[(size_t)(r0 + ty + j) * Cs + c0 + tx];
    __syncthreads();
    for (int j = 0; j < 32; j += 8)
      out[(size_t)(c0 + ty + j) * D_ + r0 + tx] = f2b(t[tx][ty + j]);
  } else {                              // ---- wjl: fused JL weights ----
    const int lb = bid - 2560;          // 0..127
    const int part = lb >> 6;           // 0 = Q, 1 = K
    const int h = (lb >> 2) & 15;
    const int dc = lb & 3;
    for (int i = tid; i < 32 * 64; i += 256) shmem[i] = Sp[i];
    __syncthreads();
    const float scale = part ? 1.0f : 0.125f * 1.44269504f;
    const int d = dc * 256 + tid;
    float w[64];
    const float* src = W_attn + (size_t)d * N3 + part * D_ + h * 64;
    for (int j = 0; j < 16; ++j) {
      float4 v = *(const float4*)&src[j * 4];
      w[j * 4 + 0] = v.x; w[j * 4 + 1] = v.y; w[j * 4 + 2] = v.z; w[j * 4 + 3] = v.w;
    }
    const int nbase = part * 512 + h * 32;
    for (int kjl = 0; kjl < 32; ++kjl) {
      float acc = 0.f;
      for (int hd = 0; hd < 64; ++hd) acc += w[hd] * shmem[kjl * 64 + hd];
      Bt2[(size_t)(nbase + kjl) * D_ + d] = f2b(acc * scale);
    }
    if (dc == 0 && tid < 32) {
      float acc = 0.f;
      for (int hd = 0; hd < 64; ++hd) acc += b_attn[part * D_ + h * 64 + hd] * shmem[tid * 64 + hd];
      bias2[nbase + tid] = acc * scale;
    }
  }
}

// ---------------- fused qkv+JL GEMM: 128x128 tiles, BK=64, TRUE double-buffer ----------------
__global__ __launch_bounds__(256, 2)
void qkv2_gemm_kernel(const unsigned short* __restrict__ A,
                      const unsigned short* __restrict__ Bt,
                      const float* __restrict__ b_attn,
                      const float* __restrict__ bias2,
                      unsigned short* __restrict__ Qjl,
                      unsigned short* __restrict__ Kjl,
                      unsigned short* __restrict__ Vc) {
  __shared__ __align__(16) unsigned short As[2][2 * 128 * 32];   // [buf][ks][row][32k]
  __shared__ __align__(16) unsigned short Bs[2][2 * 128 * 32];
  const int tid = threadIdx.x;
  const int lane = tid & 63, wv = tid >> 6;
  const int quad = lane >> 4, col = lane & 15;
  const int wm = wv >> 1, wn = wv & 1;
  const int m0 = blockIdx.y * 128, n0 = blockIdx.x * 128;

  floatx4 acc[4][4] = {};

#define STAGE_AB(bu, kk) do {                                               \
    for (int it = 0; it < 4; ++it) {                                        \
      int c = it * 256 + tid;            /* 0..1023 */                      \
      int ks = c >> 9, row = (c >> 2) & 127, kc = c & 3;                    \
      async16(A + (size_t)(m0 + row) * D_ + (kk) + ks * 32 + kc * 8,        \
              (unsigned short*)As + (bu) * 8192 + c * 8);                   \
    }                                                                       \
    for (int it = 0; it < 4; ++it) {                                        \
      int c = it * 256 + tid;                                               \
      int ks = c >> 9, row = (c >> 2) & 127, kc = c & 3;                    \
      async16(Bt + (size_t)(n0 + row) * D_ + (kk) + ks * 32 + kc * 8,       \
              (unsigned short*)Bs + (bu) * 8192 + c * 8);                   \
    }                                                                       \
  } while (0)

  // prologue: stage tile 0
  STAGE_AB(0, 0);
  asm volatile("s_waitcnt vmcnt(0)" ::: "memory");
  __builtin_amdgcn_s_barrier();

  int buf = 0;
  for (int kt = 0; kt < 16; ++kt) {
    if (kt + 1 < 16) STAGE_AB(buf ^ 1, (kt + 1) * 64);   // prefetch overlaps compute

    const unsigned short* Ab = (const unsigned short*)As + buf * 8192;
    const unsigned short* Bb = (const unsigned short*)Bs + buf * 8192;
    for (int ks = 0; ks < 2; ++ks) {
      bf16x8 af[4], bfr[4];
      for (int mt = 0; mt < 4; ++mt)
        af[mt] = *(const bf16x8*)&Ab[ks * 4096 + (wm * 64 + mt * 16 + col) * 32 + quad * 8];
      for (int nt = 0; nt < 4; ++nt)
        bfr[nt] = *(const bf16x8*)&Bb[ks * 4096 + (wn * 64 + nt * 16 + col) * 32 + quad * 8];
      __builtin_amdgcn_s_setprio(1);
      for (int mt = 0; mt < 4; ++mt)
        for (int nt = 0; nt < 4; ++nt)
          acc[mt][nt] = __builtin_amdgcn_mfma_f32_16x16x32_bf16(
              af[mt], bfr[nt], acc[mt][nt], 0, 0, 0);
      __builtin_amdgcn_s_setprio(0);
    }

    asm volatile("s_waitcnt vmcnt(0)" ::: "memory");
    __builtin_amdgcn_s_barrier();
    buf ^= 1;
  }
#undef STAGE_AB

  const int pq = n0 >> 9;  // 0=Q, 1=K, >=2 -> V
  for (int mt = 0; mt < 4; ++mt) {
    int gm0 = m0 + wm * 64 + mt * 16 + quad * 4;
    int b = gm0 >> 11, s = gm0 & (S_ - 1);
    for (int nt = 0; nt < 4; ++nt) {
      int gn = n0 + wn * 64 + nt * 16 + col;
      if (pq >= 2) {
        int vcol = gn - 1024;
        float bs = b_attn[2048 + vcol];
        int h = vcol >> 6, hd = vcol & 63;
        short4v vv;
        for (int i = 0; i < 4; ++i)
          vv[i] = (short)f2b(acc[mt][nt][i] + bs);
        size_t idx = ((((size_t)(b * H_ + h) * 64 + (s >> 5)) * 64 + hd) * 32 + (s & 31));
        *(short4v*)&Vc[idx] = vv;
      } else {
        float bs = bias2[gn];
        int gl = gn & 511;
        int h = gl >> 5, kjl = gl & 31;
        unsigned short* dst = pq ? Kjl : Qjl;
        size_t base = ((size_t)(b * H_ + h) * S_ + s) * KJL + kjl;
        for (int i = 0; i < 4; ++i)
          dst[base + (size_t)i * KJL] = f2b(acc[mt][nt][i] + bs);
      }
    }
  }
}

// ---------------- flash attention, in-register P (T12): no P-LDS round-trip ----------------
// ROUND 22 DIAGNOSIS: attn is LDS-PIPE-bound (per wave-chunk: 28 b128 + 8 b64 ~= 384
// DS-pipe cycles; per CU 136 wave-chunks => ~52K + ~18K conflict cycles of the 104K
// total). MfmaUtil 11% / VALU 23% are symptoms. The P LDS round-trip (write -> lgkm
// wait -> reread as PV B-operand) is pure overhead.
// FIX (zero-cross-lane T12): with swapped QK (sc: q=l15, key=16*sm+quad*4+i), choose
// the PV key-permutation sigma(quad,e) = 32ks + 16*(e>>2) + quad*4 + (e&3). Then the
// PV A-fragment slot (quad,e) = sc[2ks+(e>>2)][e&3] OF THE SAME LANE -> the A-operand
// is a pure register repack (no LDS, no shfl). B-operand = V read as 2 x b64 per
// fragment (both 8B runs contiguous in the existing Vc chunk layout). sigma is a
// bijection over the 32 k-slots so the dot product is exact; A and B agree on sigma.
// Deltas/wave-chunk: -8 P-writes, -4 bp b128 reads, -all P-strip conflicts, -1 serial
// lgkm wait. Epilogue: o now has q=quad*4+i; inv redistributed by 4 bpermutes; output
// transposed via a wave-private 2KB strip (swizzle XOR verified both sides).
// LDS 56KB (P strips deleted) -> 2 blocks/CU. Geometry/pairing/staging = r19 (passed).
// LESSONS: r13 reg-prefetch spills; r11 no global merge; r8 no min-wave cap; r5 no
// runtime-indexed reg arrays (all loops fully unrollable, constant trip counts).
__global__ __launch_bounds__(256, 2)
void attn_kernel(const unsigned short* __restrict__ Qjl,
                 const unsigned short* __restrict__ Kjl,
                 const unsigned short* __restrict__ Vc,
                 unsigned short* __restrict__ AO) {
  __shared__ __align__(16) unsigned short Kb[2][4096];   // [128 keys][32 kjl] x2 = 16 KB
  __shared__ __align__(16) unsigned short Vb[2][8192];   // [4][64 hd][32 s]  x2 = 32 KB
  __shared__ __align__(16) unsigned short Es[4][1024];   // per-wave epilogue strip [16 q][64 hd] = 8 KB
  const int tid = threadIdx.x;
  const int lane = tid & 63, wv = tid >> 6;              // wv 0..3
  const int quad = lane >> 4, l15 = lane & 15;

  const int blk = blockIdx.x;            // 0..511
  const int bh = blk & 31;               // bh % 8 == xcd under round-robin: L2 locality
  const int v = blk >> 5;                // 0..15
  const int b = bh >> 4, h = bh & 15;

  const unsigned short* Kg = Kjl + (size_t)bh * S_ * KJL;        // [2048][32]
  const unsigned short* Vg = Vc + (size_t)bh * (64 * 64 * 32);   // [64][64][32]

  char* Ew = (char*)&Es[wv][0];          // 2048 B wave-private epilogue strip
  const floatx4 zz = {0.f, 0.f, 0.f, 0.f};

#define STAGE(bu, c) do {                                                   \
    const char* ks_ = (const char*)(Kg + (size_t)(c) * 4096);               \
    const char* vs_ = (const char*)(Vg + (size_t)(c) * 8192);               \
    char* kd_ = (char*)&Kb[bu][0];                                          \
    char* vd_ = (char*)&Vb[bu][0];                                          \
    async16(ks_ + tid * 16,         kd_ + tid * 16);                        \
    async16(ks_ + tid * 16 + 4096,  kd_ + tid * 16 + 4096);                 \
    async16(vs_ + tid * 16,         vd_ + tid * 16);                        \
    async16(vs_ + tid * 16 + 4096,  vd_ + tid * 16 + 4096);                 \
    async16(vs_ + tid * 16 + 8192,  vd_ + tid * 16 + 8192);                 \
    async16(vs_ + tid * 16 + 12288, vd_ + tid * 16 + 12288);                \
  } while (0)

  for (int ph = 0; ph < 2; ++ph) {
    const int gv = ph ? (31 - v) : v;    // 64-row group 0..31
    const int t16 = gv * 4 + wv;         // 16-row tile: rows t16*16..t16*16+15
    const int nch = (gv >> 1) + 1;       // chunks of 128 keys (identical for all 4 waves)
    const int lastc = nch - 1;
    const int qbase = (gv & 1) * 64 + wv * 16;  // row offset within last chunk's keys

    bf16x8 aq = *(const bf16x8*)&Qjl[(size_t)(bh * S_ + t16 * 16 + l15) * KJL + quad * 8];

    floatx4 o[4] = {};                   // o[nb][i]: hd = l15+16nb, q = t16*16+quad*4+i
    floatx4 psum = {};

    // prologue: stage chunk 0
    STAGE(0, 0);
    asm volatile("s_waitcnt vmcnt(0)" ::: "memory");
    __builtin_amdgcn_s_barrier();

    int cur = 0;
    for (int kt = 0; kt < nch; ++kt) {
      if (kt + 1 < nch) STAGE(cur ^ 1, kt + 1);   // prefetch overlaps compute

      const char* Kc = (const char*)&Kb[cur][0];
      const char* Vl = (const char*)&Vb[cur][0];

      // ---- QK^T: sc[sm][i] = S[key = 16sm+quad*4+i][q = l15] ----
      bf16x8 ak[8];
      for (int sm = 0; sm < 8; ++sm)
        ak[sm] = *(const bf16x8*)(Kc + (sm * 16 + l15) * 64 + quad * 16);

      floatx4 sc[8];
      __builtin_amdgcn_s_setprio(1);
      for (int sm = 0; sm < 8; ++sm)
        sc[sm] = __builtin_amdgcn_mfma_f32_16x16x32_bf16(ak[sm], aq, zz, 0, 0, 0);
      __builtin_amdgcn_s_setprio(0);

      if (kt == lastc) {                 // causal mask within final chunk
        int qloc = qbase + l15;
        for (int sm = 0; sm < 8; ++sm)
          for (int i = 0; i < 4; ++i)
            if (sm * 16 + quad * 4 + i > qloc) sc[sm][i] = -1e30f;
      }

      // ---- softmax numerators -> packed bf16 REGISTERS (no LDS) ----
      unsigned int pk[8][2];
      for (int sm = 0; sm < 8; ++sm) {
        float p0 = __builtin_amdgcn_exp2f(sc[sm][0]);
        float p1 = __builtin_amdgcn_exp2f(sc[sm][1]);
        float p2 = __builtin_amdgcn_exp2f(sc[sm][2]);
        float p3 = __builtin_amdgcn_exp2f(sc[sm][3]);
        psum[0] += p0; psum[1] += p1; psum[2] += p2; psum[3] += p3;
        pk[sm][0] = pkbf(p0, p1);
        pk[sm][1] = pkbf(p2, p3);
      }

      // ---- PV (swapped: A=P from regs, B=V via 2xb64): o[nb] over keys ----
      for (int ks = 0; ks < 4; ++ks) {
        union { unsigned int u[4]; bf16x8 v8; } pa;
        pa.u[0] = pk[2 * ks][0];     pa.u[1] = pk[2 * ks][1];
        pa.u[2] = pk[2 * ks + 1][0]; pa.u[3] = pk[2 * ks + 1][1];
        __builtin_amdgcn_s_setprio(1);
        for (int nb = 0; nb < 4; ++nb) {
          const char* vb_ = Vl + ks * 4096 + (l15 + 16 * nb) * 64 + quad * 8;
          union { unsigned long long q[2]; bf16x8 v8; } vf;
          vf.q[0] = *(const unsigned long long*)(vb_);
          vf.q[1] = *(const unsigned long long*)(vb_ + 32);
          o[nb] = __builtin_amdgcn_mfma_f32_16x16x32_bf16(pa.v8, vf.v8, o[nb], 0, 0, 0);
        }
        __builtin_amdgcn_s_setprio(0);
      }

      asm volatile("s_waitcnt vmcnt(0)" ::: "memory");
      __builtin_amdgcn_s_barrier();
      cur ^= 1;
    }

    // ---- rowsum (q = l15), then redistribute inv to q = quad*4+i lanes ----
    float l0 = psum[0] + psum[1] + psum[2] + psum[3];
    l0 += __shfl_xor(l0, 16, 64);
    l0 += __shfl_xor(l0, 32, 64);
    float inv = 1.f / l0;
    float inv0 = __shfl(inv, quad * 4 + 0, 64);
    float inv1 = __shfl(inv, quad * 4 + 1, 64);
    float inv2 = __shfl(inv, quad * 4 + 2, 64);
    float inv3 = __shfl(inv, quad * 4 + 3, 64);

    // ---- normalize, transpose via own strip [16 q][64 hd] (swizzled), write AO ----
    for (int nb = 0; nb < 4; ++nb) {
      floatx4 ov = o[nb];
      ov[0] *= inv0; ov[1] *= inv1; ov[2] *= inv2; ov[3] *= inv3;
      for (int i = 0; i < 4; ++i) {
        int qrow = quad * 4 + i;
        int byte = qrow * 128 + (l15 + 16 * nb) * 2;
        byte ^= (qrow & 7) << 4;
        *(unsigned short*)(Ew + byte) = f2b(ov[i]);
      }
    }
    asm volatile("s_waitcnt lgkmcnt(0)" ::: "memory");
    {
      int q = lane >> 2, j = lane & 3;
      size_t gbase = ((size_t)(b * S_ + t16 * 16 + q)) * D_ + h * HD_;
      for (int half = 0; half < 2; ++half) {
        bf16x8 vv = *(const bf16x8*)(Ew + q * 128 + ((half * 64 + j * 16) ^ ((q & 7) << 4)));
        *(bf16x8*)&AO[gbase + half * 32 + j * 8] = vv;
      }
    }
  }
#undef STAGE
}

// ---------------- output projection: 64x128 tiles, BK=64, TRUE double-buffer ----------------
__global__ __launch_bounds__(256, 2)
void proj_gemm_kernel(const unsigned short* __restrict__ A,
                      const unsigned short* __restrict__ Bt,
                      const float* __restrict__ bias,
                      float* __restrict__ out) {
  __shared__ __align__(16) unsigned short As[2][2 * 64 * 32];    // [buf][ks][row][32k]
  __shared__ __align__(16) unsigned short Bs[2][2 * 128 * 32];
  const int tid = threadIdx.x;
  const int lane = tid & 63, wv = tid >> 6;
  const int quad = lane >> 4, col = lane & 15;
  const int wm = wv >> 1, wn = wv & 1;
  const int m0 = blockIdx.y * 64, n0 = blockIdx.x * 128;

  floatx4 acc[2][4] = {};

#define STAGE_AB(bu, kk) do {                                               \
    for (int it = 0; it < 2; ++it) {     /* A: 64 rows x 64 k */            \
      int c = it * 256 + tid;                                               \
      int ks = c >> 8, row = (c >> 2) & 63, kc = c & 3;                     \
      async16(A + (size_t)(m0 + row) * D_ + (kk) + ks * 32 + kc * 8,        \
              (unsigned short*)As + (bu) * 4096 + c * 8);                   \
    }                                                                       \
    for (int it = 0; it < 4; ++it) {     /* B: 128 rows x 64 k */           \
      int c = it * 256 + tid;                                               \
      int ks = c >> 9, row = (c >> 2) & 127, kc = c & 3;                    \
      async16(Bt + (size_t)(n0 + row) * D_ + (kk) + ks * 32 + kc * 8,       \
              (unsigned short*)Bs + (bu) * 8192 + c * 8);                   \
    }                                                                       \
  } while (0)

  STAGE_AB(0, 0);
  asm volatile("s_waitcnt vmcnt(0)" ::: "memory");
  __builtin_amdgcn_s_barrier();

  int buf = 0;
  for (int kt = 0; kt < 16; ++kt) {
    if (kt + 1 < 16) STAGE_AB(buf ^ 1, (kt + 1) * 64);

    const unsigned short* Ab = (const unsigned short*)As + buf * 4096;
    const unsigned short* Bb = (const unsigned short*)Bs + buf * 8192;
    for (int ks = 0; ks < 2; ++ks) {
      bf16x8 af[2], bfr[4];
      for (int mt = 0; mt < 2; ++mt)
        af[mt] = *(const bf16x8*)&Ab[ks * 2048 + (wm * 32 + mt * 16 + col) * 32 + quad * 8];
      for (int nt = 0; nt < 4; ++nt)
        bfr[nt] = *(const bf16x8*)&Bb[ks * 4096 + (wn * 64 + nt * 16 + col) * 32 + quad * 8];
      __builtin_amdgcn_s_setprio(1);
      for (int mt = 0; mt < 2; ++mt)
        for (int nt = 0; nt < 4; ++nt)
          acc[mt][nt] = __builtin_amdgcn_mfma_f32_16x16x32_bf16(
              af[mt], bfr[nt], acc[mt][nt], 0, 0, 0);
      __builtin_amdgcn_s_setprio(0);
    }

    asm volatile("s_waitcnt vmcnt(0)" ::: "memory");
    __builtin_amdgcn_s_barrier();
    buf ^= 1;
  }
#undef STAGE_AB

  for (int mt = 0; mt < 2; ++mt) {
    int gm0 = m0 + wm * 32 + mt * 16 + quad * 4;
    for (int nt = 0; nt < 4; ++nt) {
      int gn = n0 + wn * 64 + nt * 16 + col;
      float bs = bias[gn];
      for (int i = 0; i < 4; ++i)
        out[(size_t)(gm0 + i) * D_ + gn] = acc[mt][nt][i] + bs;
    }
  }
}

extern "C" void kernel_launch(void* const* d_in, const int* in_sizes, int n_in,
                              void* d_out, int out_size, void* d_ws, size_t ws_size,
                              hipStream_t stream) {
  (void)in_sizes; (void)n_in; (void)out_size; (void)ws_size;
  const float* hidden = (const float*)d_in[0];
  const float* W_attn = (const float*)d_in[1];
  const float* b_attn = (const float*)d_in[2];
  const float* S_proj = (const float*)d_in[3];
  const float* W_proj = (const float*)d_in[4];
  const float* b_proj = (const float*)d_in[5];
  float* out = (float*)d_out;

  char* ws = (char*)d_ws;
  unsigned short* hB    = (unsigned short*)(ws);                    //  8 MB
  unsigned short* Bt2   = (unsigned short*)(ws + (8u << 20));       //  4 MB
  unsigned short* WpT   = (unsigned short*)(ws + (12u << 20));      //  2 MB
  float*          bias2 = (float*)         (ws + (14u << 20));      //  4 KB
  unsigned short* Qjl   = (unsigned short*)(ws + (15u << 20));      //  4 MB
  unsigned short* Kjl   = (unsigned short*)(ws + (19u << 20));      //  4 MB
  unsigned short* Vc    = (unsigned short*)(ws + (23u << 20));      //  8 MB
  unsigned short* AO    = (unsigned short*)(ws + (31u << 20));      //  8 MB

  prep_kernel<<<2688, 256, 0, stream>>>(hidden, hB, W_attn, b_attn, S_proj,
                                        W_proj, Bt2, WpT, bias2);
  qkv2_gemm_kernel<<<dim3(N2 / 128, (B_ * S_) / 128), 256, 0, stream>>>(
      hB, Bt2, b_attn, bias2, Qjl, Kjl, Vc);
  attn_kernel<<<512, 256, 0, stream>>>(Qjl, Kjl, Vc, AO);
  proj_gemm_kernel<<<dim3(D_ / 128, (B_ * S_) / 64), 256, 0, stream>>>(
      AO, WpT, b_proj, out);
}

// Round 13
// 178.343 us; speedup vs baseline: 1.2173x; 1.2173x over previous
//
#include <hip/hip_runtime.h>
#include <hip/hip_bf16.h>
#include <stdint.h>

#define B_ 2
#define S_ 2048
#define D_ 1024
#define H_ 16
#define HD_ 64
#define KJL 32
#define N3 3072
#define N2 2048

typedef __attribute__((ext_vector_type(8))) __bf16 bf16x8;
typedef __attribute__((ext_vector_type(4))) float floatx4;
typedef __attribute__((ext_vector_type(4))) short short4v;
typedef __attribute__((ext_vector_type(2))) unsigned int uint2v;

__device__ __forceinline__ unsigned short f2b(float x) {
  union { float f; unsigned u; } v; v.f = x;
  unsigned r = v.u + 0x7fffu + ((v.u >> 16) & 1u);
  return (unsigned short)(r >> 16);
}

// pack two floats to packed bf16 (round via +0x8000): hi<<16 | lo
__device__ __forceinline__ unsigned int pkbf(float lo, float hi) {
  union { float f; unsigned u; } a, b;
  a.f = lo; b.f = hi;
  return __builtin_amdgcn_perm(b.u + 0x8000u, a.u + 0x8000u, 0x07060302u);
}

__device__ __forceinline__ void async16(const void* g, void* l) {
  __builtin_amdgcn_global_load_lds((__attribute__((address_space(1))) void*)(g),
                                   (__attribute__((address_space(3))) void*)(l),
                                   16, 0, 0);
}

// ---------------- fused prep: cvt4 | tcvt(V cols) | tcvt(W_proj) | wjl ----------------
__global__ __launch_bounds__(256)
void prep_kernel(const float* __restrict__ hidden, unsigned short* __restrict__ hB,
                 const float* __restrict__ W_attn, const float* __restrict__ b_attn,
                 const float* __restrict__ Sp, const float* __restrict__ W_proj,
                 unsigned short* __restrict__ Bt2, unsigned short* __restrict__ WpT,
                 float* __restrict__ bias2) {
  __shared__ float shmem[2048];
  const int bid = blockIdx.x;
  const int tid = threadIdx.x;

  if (bid < 512) {                      // ---- cvt4: hidden -> hB ----
    const int n4 = (B_ * S_ * D_) / 4;
    int i = bid * 256 + tid;
    for (; i < n4; i += 512 * 256) {
      float4 v = *(const float4*)(hidden + 4 * (size_t)i);
      short4v o = {(short)f2b(v.x), (short)f2b(v.y), (short)f2b(v.z), (short)f2b(v.w)};
      *(short4v*)(hB + 4 * (size_t)i) = o;
    }
  } else if (bid < 2560) {              // ---- tcvt: 32x32 transpose-convert tiles ----
    const float* in;
    unsigned short* out;
    int Cs, local;
    if (bid < 1536) { local = bid - 512;  in = W_attn + 2048; out = Bt2 + 1024 * 1024; Cs = N3; }
    else            { local = bid - 1536; in = W_proj;        out = WpT;               Cs = D_; }
    float (*t)[33] = (float(*)[33])shmem;
    int c0 = (local & 31) * 32, r0 = (local >> 5) * 32;
    int tx = tid & 31, ty = tid >> 5;
    for (int j = 0; j < 32; j += 8)
      t[ty + j][tx] = in[(size_t)(r0 + ty + j) * Cs + c0 + tx];
    __syncthreads();
    for (int j = 0; j < 32; j += 8)
      out[(size_t)(c0 + ty + j) * D_ + r0 + tx] = f2b(t[tx][ty + j]);
  } else {                              // ---- wjl: fused JL weights ----
    const int lb = bid - 2560;          // 0..127
    const int part = lb >> 6;           // 0 = Q, 1 = K
    const int h = (lb >> 2) & 15;
    const int dc = lb & 3;
    for (int i = tid; i < 32 * 64; i += 256) shmem[i] = Sp[i];
    __syncthreads();
    const float scale = part ? 1.0f : 0.125f * 1.44269504f;
    const int d = dc * 256 + tid;
    float w[64];
    const float* src = W_attn + (size_t)d * N3 + part * D_ + h * 64;
    for (int j = 0; j < 16; ++j) {
      float4 v = *(const float4*)&src[j * 4];
      w[j * 4 + 0] = v.x; w[j * 4 + 1] = v.y; w[j * 4 + 2] = v.z; w[j * 4 + 3] = v.w;
    }
    const int nbase = part * 512 + h * 32;
    for (int kjl = 0; kjl < 32; ++kjl) {
      float acc = 0.f;
      for (int hd = 0; hd < 64; ++hd) acc += w[hd] * shmem[kjl * 64 + hd];
      Bt2[(size_t)(nbase + kjl) * D_ + d] = f2b(acc * scale);
    }
    if (dc == 0 && tid < 32) {
      float acc = 0.f;
      for (int hd = 0; hd < 64; ++hd) acc += b_attn[part * D_ + h * 64 + hd] * shmem[tid * 64 + hd];
      bias2[nbase + tid] = acc * scale;
    }
  }
}

// ---------------- fused qkv+JL GEMM: 128x128 tiles, BK=64 ----------------
__global__ __launch_bounds__(256, 2)
void qkv2_gemm_kernel(const unsigned short* __restrict__ A,
                      const unsigned short* __restrict__ Bt,
                      const float* __restrict__ b_attn,
                      const float* __restrict__ bias2,
                      unsigned short* __restrict__ Qjl,
                      unsigned short* __restrict__ Kjl,
                      unsigned short* __restrict__ Vc) {
  __shared__ __align__(16) unsigned short As[2][128 * 32];
  __shared__ __align__(16) unsigned short Bs[2][128 * 32];
  const int tid = threadIdx.x;
  const int lane = tid & 63, wv = tid >> 6;
  const int quad = lane >> 4, col = lane & 15;
  const int wm = wv >> 1, wn = wv & 1;
  const int m0 = blockIdx.y * 128, n0 = blockIdx.x * 128;

  floatx4 acc[4][4] = {};

  for (int kk = 0; kk < D_; kk += 64) {
    for (int it = 0; it < 4; ++it) {
      int c = it * 256 + tid;            // 0..1023
      int ks = c >> 9, row = (c >> 2) & 127, kc = c & 3;
      async16(A + (size_t)(m0 + row) * D_ + kk + ks * 32 + kc * 8,
              (unsigned short*)As + c * 8);
    }
    for (int it = 0; it < 4; ++it) {
      int c = it * 256 + tid;
      int ks = c >> 9, row = (c >> 2) & 127, kc = c & 3;
      async16(Bt + (size_t)(n0 + row) * D_ + kk + ks * 32 + kc * 8,
              (unsigned short*)Bs + c * 8);
    }
    asm volatile("s_waitcnt vmcnt(0)" ::: "memory");
    __syncthreads();
    for (int ks = 0; ks < 2; ++ks) {
      bf16x8 af[4], bfr[4];
      for (int mt = 0; mt < 4; ++mt)
        af[mt] = *(const bf16x8*)&As[ks][(wm * 64 + mt * 16 + col) * 32 + quad * 8];
      for (int nt = 0; nt < 4; ++nt)
        bfr[nt] = *(const bf16x8*)&Bs[ks][(wn * 64 + nt * 16 + col) * 32 + quad * 8];
      for (int mt = 0; mt < 4; ++mt)
        for (int nt = 0; nt < 4; ++nt)
          acc[mt][nt] = __builtin_amdgcn_mfma_f32_16x16x32_bf16(
              af[mt], bfr[nt], acc[mt][nt], 0, 0, 0);
    }
    __syncthreads();
  }

  const int pq = n0 >> 9;  // 0=Q, 1=K, >=2 -> V
  for (int mt = 0; mt < 4; ++mt) {
    int gm0 = m0 + wm * 64 + mt * 16 + quad * 4;
    int b = gm0 >> 11, s = gm0 & (S_ - 1);
    for (int nt = 0; nt < 4; ++nt) {
      int gn = n0 + wn * 64 + nt * 16 + col;
      if (pq >= 2) {
        int vcol = gn - 1024;
        float bs = b_attn[2048 + vcol];
        int h = vcol >> 6, hd = vcol & 63;
        short4v vv;
        for (int i = 0; i < 4; ++i)
          vv[i] = (short)f2b(acc[mt][nt][i] + bs);
        size_t idx = ((((size_t)(b * H_ + h) * 64 + (s >> 5)) * 64 + hd) * 32 + (s & 31));
        *(short4v*)&Vc[idx] = vv;
      } else {
        float bs = bias2[gn];
        int gl = gn & 511;
        int h = gl >> 5, kjl = gl & 31;
        unsigned short* dst = pq ? Kjl : Qjl;
        size_t base = ((size_t)(b * H_ + h) * S_ + s) * KJL + kjl;
        for (int i = 0; i < 4; ++i)
          dst[base + (size_t)i * KJL] = f2b(acc[mt][nt][i] + bs);
      }
    }
  }
}

// ---------------- 2-blocks/CU flash attention: 4 waves, 64 rows/block, decoupled barriers ----------------
// BEST MEASURED VERSION (round 9: 177.886 us total). Restored verbatim after round 12's
// in-register-P variant regressed attn 43.5 -> 75.3 us: its V b64 reads at hd*64+quad*8
// put all 16 l15-lanes on a 64B stride = 8-way bank conflict (SQ_LDS_BANK_CONFLICT
// 4.5M -> 32.3M). LESSON: b128 reads at (row*64B, quad*16B) are at the wave64 floor;
// b64 reads with row-stride 64B are 8-way conflicted -- keep V consumption in b128 form.
// Grid 512 = 32 bh x 16 v; block v runs 64-row group v then 31-v => 17 chunks/block by
// construction. LDS 64KB -> 2 blocks/CU with decoupled barrier/vmcnt domains.
// LESSONS: r13 reg-prefetch spills; r11 no global merge; r8 no min-wave cap; r5 no
// runtime-indexed reg arrays.
__global__ __launch_bounds__(256, 2)
void attn_kernel(const unsigned short* __restrict__ Qjl,
                 const unsigned short* __restrict__ Kjl,
                 const unsigned short* __restrict__ Vc,
                 unsigned short* __restrict__ AO) {
  __shared__ __align__(16) unsigned short Kb[2][4096];   // [128 keys][32 kjl] x2 = 16 KB
  __shared__ __align__(16) unsigned short Vb[2][8192];   // [4][64 hd][32 s]  x2 = 32 KB
  __shared__ __align__(16) unsigned short Ps[4][2048];   // per-wave strip [16 q][128 k] = 16 KB
  const int tid = threadIdx.x;
  const int lane = tid & 63, wv = tid >> 6;              // wv 0..3
  const int quad = lane >> 4, l15 = lane & 15;

  const int blk = blockIdx.x;            // 0..511
  const int bh = blk & 31;               // bh % 8 == xcd under round-robin: L2 locality
  const int v = blk >> 5;                // 0..15
  const int b = bh >> 4, h = bh & 15;

  const unsigned short* Kg = Kjl + (size_t)bh * S_ * KJL;        // [2048][32]
  const unsigned short* Vg = Vc + (size_t)bh * (64 * 64 * 32);   // [64][64][32]

  char* Pw = (char*)&Ps[wv][0];          // 4096 B wave-private strip
  const int pswz = l15 << 4;             // XOR swizzle bits 4-7 (involution; rows 256B)
  const floatx4 zz = {0.f, 0.f, 0.f, 0.f};

#define STAGE(bu, c) do {                                                   \
    const char* ks_ = (const char*)(Kg + (size_t)(c) * 4096);               \
    const char* vs_ = (const char*)(Vg + (size_t)(c) * 8192);               \
    char* kd_ = (char*)&Kb[bu][0];                                          \
    char* vd_ = (char*)&Vb[bu][0];                                          \
    async16(ks_ + tid * 16,         kd_ + tid * 16);                        \
    async16(ks_ + tid * 16 + 4096,  kd_ + tid * 16 + 4096);                 \
    async16(vs_ + tid * 16,         vd_ + tid * 16);                        \
    async16(vs_ + tid * 16 + 4096,  vd_ + tid * 16 + 4096);                 \
    async16(vs_ + tid * 16 + 8192,  vd_ + tid * 16 + 8192);                 \
    async16(vs_ + tid * 16 + 12288, vd_ + tid * 16 + 12288);                \
  } while (0)

  for (int ph = 0; ph < 2; ++ph) {
    const int gv = ph ? (31 - v) : v;    // 64-row group 0..31
    const int t16 = gv * 4 + wv;         // 16-row tile: rows t16*16..t16*16+15
    const int nch = (gv >> 1) + 1;       // chunks of 128 keys (identical for all 4 waves)
    const int lastc = nch - 1;
    const int qbase = (gv & 1) * 64 + wv * 16;  // row offset within last chunk's keys

    bf16x8 aq = *(const bf16x8*)&Qjl[(size_t)(bh * S_ + t16 * 16 + l15) * KJL + quad * 8];

    floatx4 o[4] = {};
    floatx4 psum = {};

    // prologue: stage chunk 0
    STAGE(0, 0);
    asm volatile("s_waitcnt vmcnt(0)" ::: "memory");
    __builtin_amdgcn_s_barrier();

    int cur = 0;
    for (int kt = 0; kt < nch; ++kt) {
      if (kt + 1 < nch) STAGE(cur ^ 1, kt + 1);   // prefetch overlaps compute

      const char* Kc = (const char*)&Kb[cur][0];
      const char* Vl = (const char*)&Vb[cur][0];

      // ---- QK^T: sc[sm][i] = S[key = sm*16+quad*4+i][q = l15] ----
      bf16x8 ak[8];
      for (int sm = 0; sm < 8; ++sm)
        ak[sm] = *(const bf16x8*)(Kc + (sm * 16 + l15) * 64 + quad * 16);

      floatx4 sc[8];
      __builtin_amdgcn_s_setprio(1);
      for (int sm = 0; sm < 8; ++sm)
        sc[sm] = __builtin_amdgcn_mfma_f32_16x16x32_bf16(ak[sm], aq, zz, 0, 0, 0);
      __builtin_amdgcn_s_setprio(0);

      if (kt == lastc) {                 // causal mask within final chunk
        int qloc = qbase + l15;
        for (int sm = 0; sm < 8; ++sm)
          for (int i = 0; i < 4; ++i)
            if (sm * 16 + quad * 4 + i > qloc) sc[sm][i] = -1e30f;
      }

      // ---- softmax numerators -> P strip (swizzled) ----
      for (int sm = 0; sm < 8; ++sm) {
        float p0 = __builtin_amdgcn_exp2f(sc[sm][0]);
        float p1 = __builtin_amdgcn_exp2f(sc[sm][1]);
        float p2 = __builtin_amdgcn_exp2f(sc[sm][2]);
        float p3 = __builtin_amdgcn_exp2f(sc[sm][3]);
        psum[0] += p0; psum[1] += p1; psum[2] += p2; psum[3] += p3;
        uint2v pk2 = {pkbf(p0, p1), pkbf(p2, p3)};
        *(uint2v*)(Pw + l15 * 256 + ((sm * 32 + quad * 8) ^ pswz)) = pk2;
      }

      // ---- PV: o[md][i] = O[hd = md*16+quad*4+i][q = l15] ----
      for (int ks = 0; ks < 4; ++ks) {
        bf16x8 bv[4];
        for (int md = 0; md < 4; ++md)
          bv[md] = *(const bf16x8*)(Vl + ks * 4096 + md * 1024 + l15 * 64 + quad * 16);
        bf16x8 bp = *(const bf16x8*)(Pw + l15 * 256 + ((ks * 64 + quad * 16) ^ pswz));
        __builtin_amdgcn_s_setprio(1);
        for (int md = 0; md < 4; ++md)
          o[md] = __builtin_amdgcn_mfma_f32_16x16x32_bf16(bv[md], bp, o[md], 0, 0, 0);
        __builtin_amdgcn_s_setprio(0);
      }

      asm volatile("s_waitcnt vmcnt(0)" ::: "memory");
      __builtin_amdgcn_s_barrier();
      cur ^= 1;
    }

    // ---- rowsum: reduce across quads (rows are l15-resident) ----
    float l0 = psum[0] + psum[1] + psum[2] + psum[3];
    l0 += __shfl_xor(l0, 16, 64);
    l0 += __shfl_xor(l0, 32, 64);
    float inv = 1.f / l0;

    // ---- normalize, transpose via own strip [16 q][64 hd], write AO ----
    {
      const int eswz = (l15 & 7) << 4;   // bank swizzle for 128B-stride rows
      for (int md = 0; md < 4; ++md) {
        uint2v t4 = {pkbf(o[md][0] * inv, o[md][1] * inv),
                     pkbf(o[md][2] * inv, o[md][3] * inv)};
        *(uint2v*)(Pw + l15 * 128 + ((md * 32 + quad * 8) ^ eswz)) = t4;
      }
      asm volatile("s_waitcnt lgkmcnt(0)" ::: "memory");
      int q = lane >> 2, j = lane & 3;
      size_t gbase = ((size_t)(b * S_ + t16 * 16 + q)) * D_ + h * HD_;
      for (int half = 0; half < 2; ++half) {
        bf16x8 vv = *(const bf16x8*)(Pw + q * 128 + ((half * 64 + j * 16) ^ ((q & 7) << 4)));
        *(bf16x8*)&AO[gbase + half * 32 + j * 8] = vv;
      }
    }
  }
#undef STAGE
}

// ---------------- output projection: 64x128 tiles, BK=64 ----------------
__global__ __launch_bounds__(256, 2)
void proj_gemm_kernel(const unsigned short* __restrict__ A,
                      const unsigned short* __restrict__ Bt,
                      const float* __restrict__ bias,
                      float* __restrict__ out) {
  __shared__ __align__(16) unsigned short As[2][64 * 32];
  __shared__ __align__(16) unsigned short Bs[2][128 * 32];
  const int tid = threadIdx.x;
  const int lane = tid & 63, wv = tid >> 6;
  const int quad = lane >> 4, col = lane & 15;
  const int wm = wv >> 1, wn = wv & 1;
  const int m0 = blockIdx.y * 64, n0 = blockIdx.x * 128;

  floatx4 acc[2][4] = {};

  for (int kk = 0; kk < D_; kk += 64) {
    for (int it = 0; it < 2; ++it) {     // A: 64 rows x 64 k = 512 chunks
      int c = it * 256 + tid;
      int ks = c >> 8, row = (c >> 2) & 63, kc = c & 3;
      async16(A + (size_t)(m0 + row) * D_ + kk + ks * 32 + kc * 8,
              (unsigned short*)As + c * 8);
    }
    for (int it = 0; it < 4; ++it) {     // B: 128 rows x 64 k = 1024 chunks
      int c = it * 256 + tid;
      int ks = c >> 9, row = (c >> 2) & 127, kc = c & 3;
      async16(Bt + (size_t)(n0 + row) * D_ + kk + ks * 32 + kc * 8,
              (unsigned short*)Bs + c * 8);
    }
    asm volatile("s_waitcnt vmcnt(0)" ::: "memory");
    __syncthreads();
    for (int ks = 0; ks < 2; ++ks) {
      bf16x8 af[2], bfr[4];
      for (int mt = 0; mt < 2; ++mt)
        af[mt] = *(const bf16x8*)&As[ks][(wm * 32 + mt * 16 + col) * 32 + quad * 8];
      for (int nt = 0; nt < 4; ++nt)
        bfr[nt] = *(const bf16x8*)&Bs[ks][(wn * 64 + nt * 16 + col) * 32 + quad * 8];
      for (int mt = 0; mt < 2; ++mt)
        for (int nt = 0; nt < 4; ++nt)
          acc[mt][nt] = __builtin_amdgcn_mfma_f32_16x16x32_bf16(
              af[mt], bfr[nt], acc[mt][nt], 0, 0, 0);
    }
    __syncthreads();
  }

  for (int mt = 0; mt < 2; ++mt) {
    int gm0 = m0 + wm * 32 + mt * 16 + quad * 4;
    for (int nt = 0; nt < 4; ++nt) {
      int gn = n0 + wn * 64 + nt * 16 + col;
      float bs = bias[gn];
      for (int i = 0; i < 4; ++i)
        out[(size_t)(gm0 + i) * D_ + gn] = acc[mt][nt][i] + bs;
    }
  }
}

extern "C" void kernel_launch(void* const* d_in, const int* in_sizes, int n_in,
                              void* d_out, int out_size, void* d_ws, size_t ws_size,
                              hipStream_t stream) {
  (void)in_sizes; (void)n_in; (void)out_size; (void)ws_size;
  const float* hidden = (const float*)d_in[0];
  const float* W_attn = (const float*)d_in[1];
  const float* b_attn = (const float*)d_in[2];
  const float* S_proj = (const float*)d_in[3];
  const float* W_proj = (const float*)d_in[4];
  const float* b_proj = (const float*)d_in[5];
  float* out = (float*)d_out;

  char* ws = (char*)d_ws;
  unsigned short* hB    = (unsigned short*)(ws);                    //  8 MB
  unsigned short* Bt2   = (unsigned short*)(ws + (8u << 20));       //  4 MB
  unsigned short* WpT   = (unsigned short*)(ws + (12u << 20));      //  2 MB
  float*          bias2 = (float*)         (ws + (14u << 20));      //  4 KB
  unsigned short* Qjl   = (unsigned short*)(ws + (15u << 20));      //  4 MB
  unsigned short* Kjl   = (unsigned short*)(ws + (19u << 20));      //  4 MB
  unsigned short* Vc    = (unsigned short*)(ws + (23u << 20));      //  8 MB
  unsigned short* AO    = (unsigned short*)(ws + (31u << 20));      //  8 MB

  prep_kernel<<<2688, 256, 0, stream>>>(hidden, hB, W_attn, b_attn, S_proj,
                                        W_proj, Bt2, WpT, bias2);
  qkv2_gemm_kernel<<<dim3(N2 / 128, (B_ * S_) / 128), 256, 0, stream>>>(
      hB, Bt2, b_attn, bias2, Qjl, Kjl, Vc);
  attn_kernel<<<512, 256, 0, stream>>>(Qjl, Kjl, Vc, AO);
  proj_gemm_kernel<<<dim3(D_ / 128, (B_ * S_) / 64), 256, 0, stream>>>(
      AO, WpT, b_proj, out);
}

// Round 16
// 176.043 us; speedup vs baseline: 1.2332x; 1.0131x over previous
//
#include <hip/hip_runtime.h>
#include <hip/hip_bf16.h>
#include <stdint.h>

#define B_ 2
#define S_ 2048
#define D_ 1024
#define H_ 16
#define HD_ 64
#define KJL 32
#define N3 3072
#define N2 2048

typedef __attribute__((ext_vector_type(8))) __bf16 bf16x8;
typedef __attribute__((ext_vector_type(4))) float floatx4;
typedef __attribute__((ext_vector_type(4))) short short4v;
typedef __attribute__((ext_vector_type(2))) unsigned int uint2v;

__device__ __forceinline__ unsigned short f2b(float x) {
  union { float f; unsigned u; } v; v.f = x;
  unsigned r = v.u + 0x7fffu + ((v.u >> 16) & 1u);
  return (unsigned short)(r >> 16);
}

// pack two floats to packed bf16 (round via +0x8000): hi<<16 | lo
__device__ __forceinline__ unsigned int pkbf(float lo, float hi) {
  union { float f; unsigned u; } a, b;
  a.f = lo; b.f = hi;
  return __builtin_amdgcn_perm(b.u + 0x8000u, a.u + 0x8000u, 0x07060302u);
}

__device__ __forceinline__ void async16(const void* g, void* l) {
  __builtin_amdgcn_global_load_lds((__attribute__((address_space(1))) void*)(g),
                                   (__attribute__((address_space(3))) void*)(l),
                                   16, 0, 0);
}

// ---------------- fused prep: cvt4 | tcvt(V cols) | tcvt(W_proj) | wjl ----------------
__global__ __launch_bounds__(256)
void prep_kernel(const float* __restrict__ hidden, unsigned short* __restrict__ hB,
                 const float* __restrict__ W_attn, const float* __restrict__ b_attn,
                 const float* __restrict__ Sp, const float* __restrict__ W_proj,
                 unsigned short* __restrict__ Bt2, unsigned short* __restrict__ WpT,
                 float* __restrict__ bias2) {
  __shared__ float shmem[2048];
  const int bid = blockIdx.x;
  const int tid = threadIdx.x;

  if (bid < 512) {                      // ---- cvt4: hidden -> hB ----
    const int n4 = (B_ * S_ * D_) / 4;
    int i = bid * 256 + tid;
    for (; i < n4; i += 512 * 256) {
      float4 v = *(const float4*)(hidden + 4 * (size_t)i);
      short4v o = {(short)f2b(v.x), (short)f2b(v.y), (short)f2b(v.z), (short)f2b(v.w)};
      *(short4v*)(hB + 4 * (size_t)i) = o;
    }
  } else if (bid < 2560) {              // ---- tcvt: 32x32 transpose-convert tiles ----
    const float* in;
    unsigned short* out;
    int Cs, local;
    if (bid < 1536) { local = bid - 512;  in = W_attn + 2048; out = Bt2 + 1024 * 1024; Cs = N3; }
    else            { local = bid - 1536; in = W_proj;        out = WpT;               Cs = D_; }
    float (*t)[33] = (float(*)[33])shmem;
    int c0 = (local & 31) * 32, r0 = (local >> 5) * 32;
    int tx = tid & 31, ty = tid >> 5;
    for (int j = 0; j < 32; j += 8)
      t[ty + j][tx] = in[(size_t)(r0 + ty + j) * Cs + c0 + tx];
    __syncthreads();
    for (int j = 0; j < 32; j += 8)
      out[(size_t)(c0 + ty + j) * D_ + r0 + tx] = f2b(t[tx][ty + j]);
  } else {                              // ---- wjl: fused JL weights ----
    const int lb = bid - 2560;          // 0..127
    const int part = lb >> 6;           // 0 = Q, 1 = K
    const int h = (lb >> 2) & 15;
    const int dc = lb & 3;
    for (int i = tid; i < 32 * 64; i += 256) shmem[i] = Sp[i];
    __syncthreads();
    const float scale = part ? 1.0f : 0.125f * 1.44269504f;
    const int d = dc * 256 + tid;
    float w[64];
    const float* src = W_attn + (size_t)d * N3 + part * D_ + h * 64;
    for (int j = 0; j < 16; ++j) {
      float4 v = *(const float4*)&src[j * 4];
      w[j * 4 + 0] = v.x; w[j * 4 + 1] = v.y; w[j * 4 + 2] = v.z; w[j * 4 + 3] = v.w;
    }
    const int nbase = part * 512 + h * 32;
    for (int kjl = 0; kjl < 32; ++kjl) {
      float acc = 0.f;
      for (int hd = 0; hd < 64; ++hd) acc += w[hd] * shmem[kjl * 64 + hd];
      Bt2[(size_t)(nbase + kjl) * D_ + d] = f2b(acc * scale);
    }
    if (dc == 0 && tid < 32) {
      float acc = 0.f;
      for (int hd = 0; hd < 64; ++hd) acc += b_attn[part * D_ + h * 64 + hd] * shmem[tid * 64 + hd];
      bias2[nbase + tid] = acc * scale;
    }
  }
}

// ---------------- fused qkv+JL GEMM: 128x128 tiles, BK=128 ----------------
// ROUND 24: BK 64 -> 128, still single-buffered (r11 proved dbuf = noise; the lever
// is the NUMBER of vmcnt(0)+barrier drains, which the m102 shape-curve shows dominate
// this 2-barrier structure at short K). K-loop 16 -> 8 iterations; per-drain MFMA
// doubles (4 ks-slices x 32 MFMA). LDS 64KB (As 32K + Bs 32K) -> 2 blocks/CU kept.
// m132's BK=128 regression was dbuf-induced occupancy loss -- avoided here.
__global__ __launch_bounds__(256, 2)
void qkv2_gemm_kernel(const unsigned short* __restrict__ A,
                      const unsigned short* __restrict__ Bt,
                      const float* __restrict__ b_attn,
                      const float* __restrict__ bias2,
                      unsigned short* __restrict__ Qjl,
                      unsigned short* __restrict__ Kjl,
                      unsigned short* __restrict__ Vc) {
  __shared__ __align__(16) unsigned short As[4 * 128 * 32];   // [ks][row][32k] = 32 KB
  __shared__ __align__(16) unsigned short Bs[4 * 128 * 32];   // 32 KB
  const int tid = threadIdx.x;
  const int lane = tid & 63, wv = tid >> 6;
  const int quad = lane >> 4, col = lane & 15;
  const int wm = wv >> 1, wn = wv & 1;
  const int m0 = blockIdx.y * 128, n0 = blockIdx.x * 128;

  floatx4 acc[4][4] = {};

  for (int kk = 0; kk < D_; kk += 128) {
    for (int it = 0; it < 8; ++it) {     // A: 128 rows x 128 k = 2048 chunks
      int c = it * 256 + tid;            // 0..2047
      int ks = c >> 9, row = (c >> 2) & 127, kc = c & 3;
      async16(A + (size_t)(m0 + row) * D_ + kk + ks * 32 + kc * 8,
              (unsigned short*)As + c * 8);
    }
    for (int it = 0; it < 8; ++it) {
      int c = it * 256 + tid;
      int ks = c >> 9, row = (c >> 2) & 127, kc = c & 3;
      async16(Bt + (size_t)(n0 + row) * D_ + kk + ks * 32 + kc * 8,
              (unsigned short*)Bs + c * 8);
    }
    asm volatile("s_waitcnt vmcnt(0)" ::: "memory");
    __syncthreads();
    for (int ks = 0; ks < 4; ++ks) {
      bf16x8 af[4], bfr[4];
      for (int mt = 0; mt < 4; ++mt)
        af[mt] = *(const bf16x8*)&As[ks * 4096 + (wm * 64 + mt * 16 + col) * 32 + quad * 8];
      for (int nt = 0; nt < 4; ++nt)
        bfr[nt] = *(const bf16x8*)&Bs[ks * 4096 + (wn * 64 + nt * 16 + col) * 32 + quad * 8];
      for (int mt = 0; mt < 4; ++mt)
        for (int nt = 0; nt < 4; ++nt)
          acc[mt][nt] = __builtin_amdgcn_mfma_f32_16x16x32_bf16(
              af[mt], bfr[nt], acc[mt][nt], 0, 0, 0);
    }
    __syncthreads();
  }

  const int pq = n0 >> 9;  // 0=Q, 1=K, >=2 -> V
  for (int mt = 0; mt < 4; ++mt) {
    int gm0 = m0 + wm * 64 + mt * 16 + quad * 4;
    int b = gm0 >> 11, s = gm0 & (S_ - 1);
    for (int nt = 0; nt < 4; ++nt) {
      int gn = n0 + wn * 64 + nt * 16 + col;
      if (pq >= 2) {
        int vcol = gn - 1024;
        float bs = b_attn[2048 + vcol];
        int h = vcol >> 6, hd = vcol & 63;
        short4v vv;
        for (int i = 0; i < 4; ++i)
          vv[i] = (short)f2b(acc[mt][nt][i] + bs);
        size_t idx = ((((size_t)(b * H_ + h) * 64 + (s >> 5)) * 64 + hd) * 32 + (s & 31));
        *(short4v*)&Vc[idx] = vv;
      } else {
        float bs = bias2[gn];
        int gl = gn & 511;
        int h = gl >> 5, kjl = gl & 31;
        unsigned short* dst = pq ? Kjl : Qjl;
        size_t base = ((size_t)(b * H_ + h) * S_ + s) * KJL + kjl;
        for (int i = 0; i < 4; ++i)
          dst[base + (size_t)i * KJL] = f2b(acc[mt][nt][i] + bs);
      }
    }
  }
}

// ---------------- 2-blocks/CU flash attention: 4 waves, 64 rows/block, decoupled barriers ----------------
// BEST MEASURED VERSION (rounds 9/13: ~178 us total) -- UNCHANGED.
// r12 lesson: b128 reads at (row*64B, quad*16B) are at the wave64 floor; b64 reads
// with 64B row-stride are 8-way conflicted (conflicts 4.5M -> 32.3M, attn 43->75us).
// Grid 512 = 32 bh x 16 v; block v runs 64-row group v then 31-v => 17 chunks/block
// by construction. LDS 64KB -> 2 blocks/CU with decoupled barrier/vmcnt domains.
// LESSONS: r13 reg-prefetch spills; r11 no global merge; r8 no min-wave cap; r5 no
// runtime-indexed reg arrays.
__global__ __launch_bounds__(256, 2)
void attn_kernel(const unsigned short* __restrict__ Qjl,
                 const unsigned short* __restrict__ Kjl,
                 const unsigned short* __restrict__ Vc,
                 unsigned short* __restrict__ AO) {
  __shared__ __align__(16) unsigned short Kb[2][4096];   // [128 keys][32 kjl] x2 = 16 KB
  __shared__ __align__(16) unsigned short Vb[2][8192];   // [4][64 hd][32 s]  x2 = 32 KB
  __shared__ __align__(16) unsigned short Ps[4][2048];   // per-wave strip [16 q][128 k] = 16 KB
  const int tid = threadIdx.x;
  const int lane = tid & 63, wv = tid >> 6;              // wv 0..3
  const int quad = lane >> 4, l15 = lane & 15;

  const int blk = blockIdx.x;            // 0..511
  const int bh = blk & 31;               // bh % 8 == xcd under round-robin: L2 locality
  const int v = blk >> 5;                // 0..15
  const int b = bh >> 4, h = bh & 15;

  const unsigned short* Kg = Kjl + (size_t)bh * S_ * KJL;        // [2048][32]
  const unsigned short* Vg = Vc + (size_t)bh * (64 * 64 * 32);   // [64][64][32]

  char* Pw = (char*)&Ps[wv][0];          // 4096 B wave-private strip
  const int pswz = l15 << 4;             // XOR swizzle bits 4-7 (involution; rows 256B)
  const floatx4 zz = {0.f, 0.f, 0.f, 0.f};

#define STAGE(bu, c) do {                                                   \
    const char* ks_ = (const char*)(Kg + (size_t)(c) * 4096);               \
    const char* vs_ = (const char*)(Vg + (size_t)(c) * 8192);               \
    char* kd_ = (char*)&Kb[bu][0];                                          \
    char* vd_ = (char*)&Vb[bu][0];                                          \
    async16(ks_ + tid * 16,         kd_ + tid * 16);                        \
    async16(ks_ + tid * 16 + 4096,  kd_ + tid * 16 + 4096);                 \
    async16(vs_ + tid * 16,         vd_ + tid * 16);                        \
    async16(vs_ + tid * 16 + 4096,  vd_ + tid * 16 + 4096);                 \
    async16(vs_ + tid * 16 + 8192,  vd_ + tid * 16 + 8192);                 \
    async16(vs_ + tid * 16 + 12288, vd_ + tid * 16 + 12288);                \
  } while (0)

  for (int ph = 0; ph < 2; ++ph) {
    const int gv = ph ? (31 - v) : v;    // 64-row group 0..31
    const int t16 = gv * 4 + wv;         // 16-row tile: rows t16*16..t16*16+15
    const int nch = (gv >> 1) + 1;       // chunks of 128 keys (identical for all 4 waves)
    const int lastc = nch - 1;
    const int qbase = (gv & 1) * 64 + wv * 16;  // row offset within last chunk's keys

    bf16x8 aq = *(const bf16x8*)&Qjl[(size_t)(bh * S_ + t16 * 16 + l15) * KJL + quad * 8];

    floatx4 o[4] = {};
    floatx4 psum = {};

    // prologue: stage chunk 0
    STAGE(0, 0);
    asm volatile("s_waitcnt vmcnt(0)" ::: "memory");
    __builtin_amdgcn_s_barrier();

    int cur = 0;
    for (int kt = 0; kt < nch; ++kt) {
      if (kt + 1 < nch) STAGE(cur ^ 1, kt + 1);   // prefetch overlaps compute

      const char* Kc = (const char*)&Kb[cur][0];
      const char* Vl = (const char*)&Vb[cur][0];

      // ---- QK^T: sc[sm][i] = S[key = sm*16+quad*4+i][q = l15] ----
      bf16x8 ak[8];
      for (int sm = 0; sm < 8; ++sm)
        ak[sm] = *(const bf16x8*)(Kc + (sm * 16 + l15) * 64 + quad * 16);

      floatx4 sc[8];
      __builtin_amdgcn_s_setprio(1);
      for (int sm = 0; sm < 8; ++sm)
        sc[sm] = __builtin_amdgcn_mfma_f32_16x16x32_bf16(ak[sm], aq, zz, 0, 0, 0);
      __builtin_amdgcn_s_setprio(0);

      if (kt == lastc) {                 // causal mask within final chunk
        int qloc = qbase + l15;
        for (int sm = 0; sm < 8; ++sm)
          for (int i = 0; i < 4; ++i)
            if (sm * 16 + quad * 4 + i > qloc) sc[sm][i] = -1e30f;
      }

      // ---- softmax numerators -> P strip (swizzled) ----
      for (int sm = 0; sm < 8; ++sm) {
        float p0 = __builtin_amdgcn_exp2f(sc[sm][0]);
        float p1 = __builtin_amdgcn_exp2f(sc[sm][1]);
        float p2 = __builtin_amdgcn_exp2f(sc[sm][2]);
        float p3 = __builtin_amdgcn_exp2f(sc[sm][3]);
        psum[0] += p0; psum[1] += p1; psum[2] += p2; psum[3] += p3;
        uint2v pk2 = {pkbf(p0, p1), pkbf(p2, p3)};
        *(uint2v*)(Pw + l15 * 256 + ((sm * 32 + quad * 8) ^ pswz)) = pk2;
      }

      // ---- PV: o[md][i] = O[hd = md*16+quad*4+i][q = l15] ----
      for (int ks = 0; ks < 4; ++ks) {
        bf16x8 bv[4];
        for (int md = 0; md < 4; ++md)
          bv[md] = *(const bf16x8*)(Vl + ks * 4096 + md * 1024 + l15 * 64 + quad * 16);
        bf16x8 bp = *(const bf16x8*)(Pw + l15 * 256 + ((ks * 64 + quad * 16) ^ pswz));
        __builtin_amdgcn_s_setprio(1);
        for (int md = 0; md < 4; ++md)
          o[md] = __builtin_amdgcn_mfma_f32_16x16x32_bf16(bv[md], bp, o[md], 0, 0, 0);
        __builtin_amdgcn_s_setprio(0);
      }

      asm volatile("s_waitcnt vmcnt(0)" ::: "memory");
      __builtin_amdgcn_s_barrier();
      cur ^= 1;
    }

    // ---- rowsum: reduce across quads (rows are l15-resident) ----
    float l0 = psum[0] + psum[1] + psum[2] + psum[3];
    l0 += __shfl_xor(l0, 16, 64);
    l0 += __shfl_xor(l0, 32, 64);
    float inv = 1.f / l0;

    // ---- normalize, transpose via own strip [16 q][64 hd], write AO ----
    {
      const int eswz = (l15 & 7) << 4;   // bank swizzle for 128B-stride rows
      for (int md = 0; md < 4; ++md) {
        uint2v t4 = {pkbf(o[md][0] * inv, o[md][1] * inv),
                     pkbf(o[md][2] * inv, o[md][3] * inv)};
        *(uint2v*)(Pw + l15 * 128 + ((md * 32 + quad * 8) ^ eswz)) = t4;
      }
      asm volatile("s_waitcnt lgkmcnt(0)" ::: "memory");
      int q = lane >> 2, j = lane & 3;
      size_t gbase = ((size_t)(b * S_ + t16 * 16 + q)) * D_ + h * HD_;
      for (int half = 0; half < 2; ++half) {
        bf16x8 vv = *(const bf16x8*)(Pw + q * 128 + ((half * 64 + j * 16) ^ ((q & 7) << 4)));
        *(bf16x8*)&AO[gbase + half * 32 + j * 8] = vv;
      }
    }
  }
#undef STAGE
}

// ---------------- output projection: 64x128 tiles, BK=128 ----------------
__global__ __launch_bounds__(256, 2)
void proj_gemm_kernel(const unsigned short* __restrict__ A,
                      const unsigned short* __restrict__ Bt,
                      const float* __restrict__ bias,
                      float* __restrict__ out) {
  __shared__ __align__(16) unsigned short As[4 * 64 * 32];    // [ks][row][32k] = 16 KB
  __shared__ __align__(16) unsigned short Bs[4 * 128 * 32];   // 32 KB
  const int tid = threadIdx.x;
  const int lane = tid & 63, wv = tid >> 6;
  const int quad = lane >> 4, col = lane & 15;
  const int wm = wv >> 1, wn = wv & 1;
  const int m0 = blockIdx.y * 64, n0 = blockIdx.x * 128;

  floatx4 acc[2][4] = {};

  for (int kk = 0; kk < D_; kk += 128) {
    for (int it = 0; it < 4; ++it) {     // A: 64 rows x 128 k = 1024 chunks
      int c = it * 256 + tid;
      int ks = c >> 8, row = (c >> 2) & 63, kc = c & 3;
      async16(A + (size_t)(m0 + row) * D_ + kk + ks * 32 + kc * 8,
              (unsigned short*)As + c * 8);
    }
    for (int it = 0; it < 8; ++it) {     // B: 128 rows x 128 k = 2048 chunks
      int c = it * 256 + tid;
      int ks = c >> 9, row = (c >> 2) & 127, kc = c & 3;
      async16(Bt + (size_t)(n0 + row) * D_ + kk + ks * 32 + kc * 8,
              (unsigned short*)Bs + c * 8);
    }
    asm volatile("s_waitcnt vmcnt(0)" ::: "memory");
    __syncthreads();
    for (int ks = 0; ks < 4; ++ks) {
      bf16x8 af[2], bfr[4];
      for (int mt = 0; mt < 2; ++mt)
        af[mt] = *(const bf16x8*)&As[ks * 2048 + (wm * 32 + mt * 16 + col) * 32 + quad * 8];
      for (int nt = 0; nt < 4; ++nt)
        bfr[nt] = *(const bf16x8*)&Bs[ks * 4096 + (wn * 64 + nt * 16 + col) * 32 + quad * 8];
      for (int mt = 0; mt < 2; ++mt)
        for (int nt = 0; nt < 4; ++nt)
          acc[mt][nt] = __builtin_amdgcn_mfma_f32_16x16x32_bf16(
              af[mt], bfr[nt], acc[mt][nt], 0, 0, 0);
    }
    __syncthreads();
  }

  for (int mt = 0; mt < 2; ++mt) {
    int gm0 = m0 + wm * 32 + mt * 16 + quad * 4;
    for (int nt = 0; nt < 4; ++nt) {
      int gn = n0 + wn * 64 + nt * 16 + col;
      float bs = bias[gn];
      for (int i = 0; i < 4; ++i)
        out[(size_t)(gm0 + i) * D_ + gn] = acc[mt][nt][i] + bs;
    }
  }
}

extern "C" void kernel_launch(void* const* d_in, const int* in_sizes, int n_in,
                              void* d_out, int out_size, void* d_ws, size_t ws_size,
                              hipStream_t stream) {
  (void)in_sizes; (void)n_in; (void)out_size; (void)ws_size;
  const float* hidden = (const float*)d_in[0];
  const float* W_attn = (const float*)d_in[1];
  const float* b_attn = (const float*)d_in[2];
  const float* S_proj = (const float*)d_in[3];
  const float* W_proj = (const float*)d_in[4];
  const float* b_proj = (const float*)d_in[5];
  float* out = (float*)d_out;

  char* ws = (char*)d_ws;
  unsigned short* hB    = (unsigned short*)(ws);                    //  8 MB
  unsigned short* Bt2   = (unsigned short*)(ws + (8u << 20));       //  4 MB
  unsigned short* WpT   = (unsigned short*)(ws + (12u << 20));      //  2 MB
  float*          bias2 = (float*)         (ws + (14u << 20));      //  4 KB
  unsigned short* Qjl   = (unsigned short*)(ws + (15u << 20));      //  4 MB
  unsigned short* Kjl   = (unsigned short*)(ws + (19u << 20));      //  4 MB
  unsigned short* Vc    = (unsigned short*)(ws + (23u << 20));      //  8 MB
  unsigned short* AO    = (unsigned short*)(ws + (31u << 20));      //  8 MB

  prep_kernel<<<2688, 256, 0, stream>>>(hidden, hB, W_attn, b_attn, S_proj,
                                        W_proj, Bt2, WpT, bias2);
  qkv2_gemm_kernel<<<dim3(N2 / 128, (B_ * S_) / 128), 256, 0, stream>>>(
      hB, Bt2, b_attn, bias2, Qjl, Kjl, Vc);
  attn_kernel<<<512, 256, 0, stream>>>(Qjl, Kjl, Vc, AO);
  proj_gemm_kernel<<<dim3(D_ / 128, (B_ * S_) / 64), 256, 0, stream>>>(
      AO, WpT, b_proj, out);
}

// Round 17
// 174.091 us; speedup vs baseline: 1.2470x; 1.0112x over previous
//
#include <hip/hip_runtime.h>
#include <hip/hip_bf16.h>
#include <stdint.h>

#define B_ 2
#define S_ 2048
#define D_ 1024
#define H_ 16
#define HD_ 64
#define KJL 32
#define N3 3072
#define N2 2048

typedef __attribute__((ext_vector_type(8))) __bf16 bf16x8;
typedef __attribute__((ext_vector_type(4))) float floatx4;
typedef __attribute__((ext_vector_type(4))) short short4v;
typedef __attribute__((ext_vector_type(2))) unsigned int uint2v;

__device__ __forceinline__ unsigned short f2b(float x) {
  union { float f; unsigned u; } v; v.f = x;
  unsigned r = v.u + 0x7fffu + ((v.u >> 16) & 1u);
  return (unsigned short)(r >> 16);
}

// pack two floats to packed bf16 (round via +0x8000): hi<<16 | lo
__device__ __forceinline__ unsigned int pkbf(float lo, float hi) {
  union { float f; unsigned u; } a, b;
  a.f = lo; b.f = hi;
  return __builtin_amdgcn_perm(b.u + 0x8000u, a.u + 0x8000u, 0x07060302u);
}

__device__ __forceinline__ void async16(const void* g, void* l) {
  __builtin_amdgcn_global_load_lds((__attribute__((address_space(1))) void*)(g),
                                   (__attribute__((address_space(3))) void*)(l),
                                   16, 0, 0);
}

// ---------------- fused prep: cvt4 | tcvt(V cols) | tcvt(W_proj) | wjl ----------------
__global__ __launch_bounds__(256)
void prep_kernel(const float* __restrict__ hidden, unsigned short* __restrict__ hB,
                 const float* __restrict__ W_attn, const float* __restrict__ b_attn,
                 const float* __restrict__ Sp, const float* __restrict__ W_proj,
                 unsigned short* __restrict__ Bt2, unsigned short* __restrict__ WpT,
                 float* __restrict__ bias2) {
  __shared__ float shmem[2048];
  const int bid = blockIdx.x;
  const int tid = threadIdx.x;

  if (bid < 512) {                      // ---- cvt4: hidden -> hB ----
    const int n4 = (B_ * S_ * D_) / 4;
    int i = bid * 256 + tid;
    for (; i < n4; i += 512 * 256) {
      float4 v = *(const float4*)(hidden + 4 * (size_t)i);
      short4v o = {(short)f2b(v.x), (short)f2b(v.y), (short)f2b(v.z), (short)f2b(v.w)};
      *(short4v*)(hB + 4 * (size_t)i) = o;
    }
  } else if (bid < 2560) {              // ---- tcvt: 32x32 transpose-convert tiles ----
    const float* in;
    unsigned short* out;
    int Cs, local;
    if (bid < 1536) { local = bid - 512;  in = W_attn + 2048; out = Bt2 + 1024 * 1024; Cs = N3; }
    else            { local = bid - 1536; in = W_proj;        out = WpT;               Cs = D_; }
    float (*t)[33] = (float(*)[33])shmem;
    int c0 = (local & 31) * 32, r0 = (local >> 5) * 32;
    int tx = tid & 31, ty = tid >> 5;
    for (int j = 0; j < 32; j += 8)
      t[ty + j][tx] = in[(size_t)(r0 + ty + j) * Cs + c0 + tx];
    __syncthreads();
    for (int j = 0; j < 32; j += 8)
      out[(size_t)(c0 + ty + j) * D_ + r0 + tx] = f2b(t[tx][ty + j]);
  } else {                              // ---- wjl: fused JL weights ----
    const int lb = bid - 2560;          // 0..127
    const int part = lb >> 6;           // 0 = Q, 1 = K
    const int h = (lb >> 2) & 15;
    const int dc = lb & 3;
    for (int i = tid; i < 32 * 64; i += 256) shmem[i] = Sp[i];
    __syncthreads();
    const float scale = part ? 1.0f : 0.125f * 1.44269504f;
    const int d = dc * 256 + tid;
    float w[64];
    const float* src = W_attn + (size_t)d * N3 + part * D_ + h * 64;
    for (int j = 0; j < 16; ++j) {
      float4 v = *(const float4*)&src[j * 4];
      w[j * 4 + 0] = v.x; w[j * 4 + 1] = v.y; w[j * 4 + 2] = v.z; w[j * 4 + 3] = v.w;
    }
    const int nbase = part * 512 + h * 32;
    for (int kjl = 0; kjl < 32; ++kjl) {
      float acc = 0.f;
      for (int hd = 0; hd < 64; ++hd) acc += w[hd] * shmem[kjl * 64 + hd];
      Bt2[(size_t)(nbase + kjl) * D_ + d] = f2b(acc * scale);
    }
    if (dc == 0 && tid < 32) {
      float acc = 0.f;
      for (int hd = 0; hd < 64; ++hd) acc += b_attn[part * D_ + h * 64 + hd] * shmem[tid * 64 + hd];
      bias2[nbase + tid] = acc * scale;
    }
  }
}

// ---------------- fused qkv+JL GEMM: 128x128 tiles, BK=128, XCD-chunked swizzle ----------------
// ROUND 27: + T1 XCD swizzle. 512 blocks = 8x64 exactly -> bijective chunked remap
// (bidx%8)*64 + bidx/8: XCD k gets 4 consecutive M-panels x all 16 N-tiles, so each
// 256KB A-panel lives in ONE XCD's L2 and the 4MB B matrix is L2-resident per XCD
// (default round-robin fetched each A-panel into 8 different L2s). Measured T1 delta
// +10-12% when inter-block operand reuse exists (m192).
// BK=128 single-buffered (r16: -2.3us vs BK=64; r11: dbuf = noise).
__global__ __launch_bounds__(256, 2)
void qkv2_gemm_kernel(const unsigned short* __restrict__ A,
                      const unsigned short* __restrict__ Bt,
                      const float* __restrict__ b_attn,
                      const float* __restrict__ bias2,
                      unsigned short* __restrict__ Qjl,
                      unsigned short* __restrict__ Kjl,
                      unsigned short* __restrict__ Vc) {
  __shared__ __align__(16) unsigned short As[4 * 128 * 32];   // [ks][row][32k] = 32 KB
  __shared__ __align__(16) unsigned short Bs[4 * 128 * 32];   // 32 KB
  const int tid = threadIdx.x;
  const int lane = tid & 63, wv = tid >> 6;
  const int quad = lane >> 4, col = lane & 15;
  const int wm = wv >> 1, wn = wv & 1;
  const int bidx = blockIdx.y * 16 + blockIdx.x;      // 0..511
  const int swz = (bidx & 7) * 64 + (bidx >> 3);      // bijective 8-XCD chunk swizzle
  const int m0 = (swz >> 4) * 128, n0 = (swz & 15) * 128;

  floatx4 acc[4][4] = {};

  for (int kk = 0; kk < D_; kk += 128) {
    for (int it = 0; it < 8; ++it) {     // A: 128 rows x 128 k = 2048 chunks
      int c = it * 256 + tid;            // 0..2047
      int ks = c >> 9, row = (c >> 2) & 127, kc = c & 3;
      async16(A + (size_t)(m0 + row) * D_ + kk + ks * 32 + kc * 8,
              (unsigned short*)As + c * 8);
    }
    for (int it = 0; it < 8; ++it) {
      int c = it * 256 + tid;
      int ks = c >> 9, row = (c >> 2) & 127, kc = c & 3;
      async16(Bt + (size_t)(n0 + row) * D_ + kk + ks * 32 + kc * 8,
              (unsigned short*)Bs + c * 8);
    }
    asm volatile("s_waitcnt vmcnt(0)" ::: "memory");
    __syncthreads();
    for (int ks = 0; ks < 4; ++ks) {
      bf16x8 af[4], bfr[4];
      for (int mt = 0; mt < 4; ++mt)
        af[mt] = *(const bf16x8*)&As[ks * 4096 + (wm * 64 + mt * 16 + col) * 32 + quad * 8];
      for (int nt = 0; nt < 4; ++nt)
        bfr[nt] = *(const bf16x8*)&Bs[ks * 4096 + (wn * 64 + nt * 16 + col) * 32 + quad * 8];
      for (int mt = 0; mt < 4; ++mt)
        for (int nt = 0; nt < 4; ++nt)
          acc[mt][nt] = __builtin_amdgcn_mfma_f32_16x16x32_bf16(
              af[mt], bfr[nt], acc[mt][nt], 0, 0, 0);
    }
    __syncthreads();
  }

  const int pq = n0 >> 9;  // 0=Q, 1=K, >=2 -> V
  for (int mt = 0; mt < 4; ++mt) {
    int gm0 = m0 + wm * 64 + mt * 16 + quad * 4;
    int b = gm0 >> 11, s = gm0 & (S_ - 1);
    for (int nt = 0; nt < 4; ++nt) {
      int gn = n0 + wn * 64 + nt * 16 + col;
      if (pq >= 2) {
        int vcol = gn - 1024;
        float bs = b_attn[2048 + vcol];
        int h = vcol >> 6, hd = vcol & 63;
        short4v vv;
        for (int i = 0; i < 4; ++i)
          vv[i] = (short)f2b(acc[mt][nt][i] + bs);
        size_t idx = ((((size_t)(b * H_ + h) * 64 + (s >> 5)) * 64 + hd) * 32 + (s & 31));
        *(short4v*)&Vc[idx] = vv;
      } else {
        float bs = bias2[gn];
        int gl = gn & 511;
        int h = gl >> 5, kjl = gl & 31;
        unsigned short* dst = pq ? Kjl : Qjl;
        size_t base = ((size_t)(b * H_ + h) * S_ + s) * KJL + kjl;
        for (int i = 0; i < 4; ++i)
          dst[base + (size_t)i * KJL] = f2b(acc[mt][nt][i] + bs);
      }
    }
  }
}

// ---------------- 2-blocks/CU flash attention: 4 waves, 64 rows/block, decoupled barriers ----------------
// BEST MEASURED VERSION (rounds 9/13/16: ~176-178 us total) -- UNCHANGED.
// r12 lesson: b128 reads at (row*64B, quad*16B) are at the wave64 floor; b64 reads
// with 64B row-stride are 8-way conflicted (conflicts 4.5M -> 32.3M, attn 43->75us).
// Grid 512 = 32 bh x 16 v; block v runs 64-row group v then 31-v => 17 chunks/block
// by construction. LDS 64KB -> 2 blocks/CU with decoupled barrier/vmcnt domains.
// LESSONS: r13 reg-prefetch spills; r11 no global merge; r8 no min-wave cap; r5 no
// runtime-indexed reg arrays.
__global__ __launch_bounds__(256, 2)
void attn_kernel(const unsigned short* __restrict__ Qjl,
                 const unsigned short* __restrict__ Kjl,
                 const unsigned short* __restrict__ Vc,
                 unsigned short* __restrict__ AO) {
  __shared__ __align__(16) unsigned short Kb[2][4096];   // [128 keys][32 kjl] x2 = 16 KB
  __shared__ __align__(16) unsigned short Vb[2][8192];   // [4][64 hd][32 s]  x2 = 32 KB
  __shared__ __align__(16) unsigned short Ps[4][2048];   // per-wave strip [16 q][128 k] = 16 KB
  const int tid = threadIdx.x;
  const int lane = tid & 63, wv = tid >> 6;              // wv 0..3
  const int quad = lane >> 4, l15 = lane & 15;

  const int blk = blockIdx.x;            // 0..511
  const int bh = blk & 31;               // bh % 8 == xcd under round-robin: L2 locality
  const int v = blk >> 5;                // 0..15
  const int b = bh >> 4, h = bh & 15;

  const unsigned short* Kg = Kjl + (size_t)bh * S_ * KJL;        // [2048][32]
  const unsigned short* Vg = Vc + (size_t)bh * (64 * 64 * 32);   // [64][64][32]

  char* Pw = (char*)&Ps[wv][0];          // 4096 B wave-private strip
  const int pswz = l15 << 4;             // XOR swizzle bits 4-7 (involution; rows 256B)
  const floatx4 zz = {0.f, 0.f, 0.f, 0.f};

#define STAGE(bu, c) do {                                                   \
    const char* ks_ = (const char*)(Kg + (size_t)(c) * 4096);               \
    const char* vs_ = (const char*)(Vg + (size_t)(c) * 8192);               \
    char* kd_ = (char*)&Kb[bu][0];                                          \
    char* vd_ = (char*)&Vb[bu][0];                                          \
    async16(ks_ + tid * 16,         kd_ + tid * 16);                        \
    async16(ks_ + tid * 16 + 4096,  kd_ + tid * 16 + 4096);                 \
    async16(vs_ + tid * 16,         vd_ + tid * 16);                        \
    async16(vs_ + tid * 16 + 4096,  vd_ + tid * 16 + 4096);                 \
    async16(vs_ + tid * 16 + 8192,  vd_ + tid * 16 + 8192);                 \
    async16(vs_ + tid * 16 + 12288, vd_ + tid * 16 + 12288);                \
  } while (0)

  for (int ph = 0; ph < 2; ++ph) {
    const int gv = ph ? (31 - v) : v;    // 64-row group 0..31
    const int t16 = gv * 4 + wv;         // 16-row tile: rows t16*16..t16*16+15
    const int nch = (gv >> 1) + 1;       // chunks of 128 keys (identical for all 4 waves)
    const int lastc = nch - 1;
    const int qbase = (gv & 1) * 64 + wv * 16;  // row offset within last chunk's keys

    bf16x8 aq = *(const bf16x8*)&Qjl[(size_t)(bh * S_ + t16 * 16 + l15) * KJL + quad * 8];

    floatx4 o[4] = {};
    floatx4 psum = {};

    // prologue: stage chunk 0
    STAGE(0, 0);
    asm volatile("s_waitcnt vmcnt(0)" ::: "memory");
    __builtin_amdgcn_s_barrier();

    int cur = 0;
    for (int kt = 0; kt < nch; ++kt) {
      if (kt + 1 < nch) STAGE(cur ^ 1, kt + 1);   // prefetch overlaps compute

      const char* Kc = (const char*)&Kb[cur][0];
      const char* Vl = (const char*)&Vb[cur][0];

      // ---- QK^T: sc[sm][i] = S[key = sm*16+quad*4+i][q = l15] ----
      bf16x8 ak[8];
      for (int sm = 0; sm < 8; ++sm)
        ak[sm] = *(const bf16x8*)(Kc + (sm * 16 + l15) * 64 + quad * 16);

      floatx4 sc[8];
      __builtin_amdgcn_s_setprio(1);
      for (int sm = 0; sm < 8; ++sm)
        sc[sm] = __builtin_amdgcn_mfma_f32_16x16x32_bf16(ak[sm], aq, zz, 0, 0, 0);
      __builtin_amdgcn_s_setprio(0);

      if (kt == lastc) {                 // causal mask within final chunk
        int qloc = qbase + l15;
        for (int sm = 0; sm < 8; ++sm)
          for (int i = 0; i < 4; ++i)
            if (sm * 16 + quad * 4 + i > qloc) sc[sm][i] = -1e30f;
      }

      // ---- softmax numerators -> P strip (swizzled) ----
      for (int sm = 0; sm < 8; ++sm) {
        float p0 = __builtin_amdgcn_exp2f(sc[sm][0]);
        float p1 = __builtin_amdgcn_exp2f(sc[sm][1]);
        float p2 = __builtin_amdgcn_exp2f(sc[sm][2]);
        float p3 = __builtin_amdgcn_exp2f(sc[sm][3]);
        psum[0] += p0; psum[1] += p1; psum[2] += p2; psum[3] += p3;
        uint2v pk2 = {pkbf(p0, p1), pkbf(p2, p3)};
        *(uint2v*)(Pw + l15 * 256 + ((sm * 32 + quad * 8) ^ pswz)) = pk2;
      }

      // ---- PV: o[md][i] = O[hd = md*16+quad*4+i][q = l15] ----
      for (int ks = 0; ks < 4; ++ks) {
        bf16x8 bv[4];
        for (int md = 0; md < 4; ++md)
          bv[md] = *(const bf16x8*)(Vl + ks * 4096 + md * 1024 + l15 * 64 + quad * 16);
        bf16x8 bp = *(const bf16x8*)(Pw + l15 * 256 + ((ks * 64 + quad * 16) ^ pswz));
        __builtin_amdgcn_s_setprio(1);
        for (int md = 0; md < 4; ++md)
          o[md] = __builtin_amdgcn_mfma_f32_16x16x32_bf16(bv[md], bp, o[md], 0, 0, 0);
        __builtin_amdgcn_s_setprio(0);
      }

      asm volatile("s_waitcnt vmcnt(0)" ::: "memory");
      __builtin_amdgcn_s_barrier();
      cur ^= 1;
    }

    // ---- rowsum: reduce across quads (rows are l15-resident) ----
    float l0 = psum[0] + psum[1] + psum[2] + psum[3];
    l0 += __shfl_xor(l0, 16, 64);
    l0 += __shfl_xor(l0, 32, 64);
    float inv = 1.f / l0;

    // ---- normalize, transpose via own strip [16 q][64 hd], write AO ----
    {
      const int eswz = (l15 & 7) << 4;   // bank swizzle for 128B-stride rows
      for (int md = 0; md < 4; ++md) {
        uint2v t4 = {pkbf(o[md][0] * inv, o[md][1] * inv),
                     pkbf(o[md][2] * inv, o[md][3] * inv)};
        *(uint2v*)(Pw + l15 * 128 + ((md * 32 + quad * 8) ^ eswz)) = t4;
      }
      asm volatile("s_waitcnt lgkmcnt(0)" ::: "memory");
      int q = lane >> 2, j = lane & 3;
      size_t gbase = ((size_t)(b * S_ + t16 * 16 + q)) * D_ + h * HD_;
      for (int half = 0; half < 2; ++half) {
        bf16x8 vv = *(const bf16x8*)(Pw + q * 128 + ((half * 64 + j * 16) ^ ((q & 7) << 4)));
        *(bf16x8*)&AO[gbase + half * 32 + j * 8] = vv;
      }
    }
  }
#undef STAGE
}

// ---------------- output projection: 64x128 tiles, BK=128, XCD-chunked swizzle ----------------
__global__ __launch_bounds__(256, 2)
void proj_gemm_kernel(const unsigned short* __restrict__ A,
                      const unsigned short* __restrict__ Bt,
                      const float* __restrict__ bias,
                      float* __restrict__ out) {
  __shared__ __align__(16) unsigned short As[4 * 64 * 32];    // [ks][row][32k] = 16 KB
  __shared__ __align__(16) unsigned short Bs[4 * 128 * 32];   // 32 KB
  const int tid = threadIdx.x;
  const int lane = tid & 63, wv = tid >> 6;
  const int quad = lane >> 4, col = lane & 15;
  const int wm = wv >> 1, wn = wv & 1;
  const int bidx = blockIdx.y * 8 + blockIdx.x;       // 0..511
  const int swz = (bidx & 7) * 64 + (bidx >> 3);      // bijective 8-XCD chunk swizzle
  const int m0 = (swz >> 3) * 64, n0 = (swz & 7) * 128;

  floatx4 acc[2][4] = {};

  for (int kk = 0; kk < D_; kk += 128) {
    for (int it = 0; it < 4; ++it) {     // A: 64 rows x 128 k = 1024 chunks
      int c = it * 256 + tid;
      int ks = c >> 8, row = (c >> 2) & 63, kc = c & 3;
      async16(A + (size_t)(m0 + row) * D_ + kk + ks * 32 + kc * 8,
              (unsigned short*)As + c * 8);
    }
    for (int it = 0; it < 8; ++it) {     // B: 128 rows x 128 k = 2048 chunks
      int c = it * 256 + tid;
      int ks = c >> 9, row = (c >> 2) & 127, kc = c & 3;
      async16(Bt + (size_t)(n0 + row) * D_ + kk + ks * 32 + kc * 8,
              (unsigned short*)Bs + c * 8);
    }
    asm volatile("s_waitcnt vmcnt(0)" ::: "memory");
    __syncthreads();
    for (int ks = 0; ks < 4; ++ks) {
      bf16x8 af[2], bfr[4];
      for (int mt = 0; mt < 2; ++mt)
        af[mt] = *(const bf16x8*)&As[ks * 2048 + (wm * 32 + mt * 16 + col) * 32 + quad * 8];
      for (int nt = 0; nt < 4; ++nt)
        bfr[nt] = *(const bf16x8*)&Bs[ks * 4096 + (wn * 64 + nt * 16 + col) * 32 + quad * 8];
      for (int mt = 0; mt < 2; ++mt)
        for (int nt = 0; nt < 4; ++nt)
          acc[mt][nt] = __builtin_amdgcn_mfma_f32_16x16x32_bf16(
              af[mt], bfr[nt], acc[mt][nt], 0, 0, 0);
    }
    __syncthreads();
  }

  for (int mt = 0; mt < 2; ++mt) {
    int gm0 = m0 + wm * 32 + mt * 16 + quad * 4;
    for (int nt = 0; nt < 4; ++nt) {
      int gn = n0 + wn * 64 + nt * 16 + col;
      float bs = bias[gn];
      for (int i = 0; i < 4; ++i)
        out[(size_t)(gm0 + i) * D_ + gn] = acc[mt][nt][i] + bs;
    }
  }
}

extern "C" void kernel_launch(void* const* d_in, const int* in_sizes, int n_in,
                              void* d_out, int out_size, void* d_ws, size_t ws_size,
                              hipStream_t stream) {
  (void)in_sizes; (void)n_in; (void)out_size; (void)ws_size;
  const float* hidden = (const float*)d_in[0];
  const float* W_attn = (const float*)d_in[1];
  const float* b_attn = (const float*)d_in[2];
  const float* S_proj = (const float*)d_in[3];
  const float* W_proj = (const float*)d_in[4];
  const float* b_proj = (const float*)d_in[5];
  float* out = (float*)d_out;

  char* ws = (char*)d_ws;
  unsigned short* hB    = (unsigned short*)(ws);                    //  8 MB
  unsigned short* Bt2   = (unsigned short*)(ws + (8u << 20));       //  4 MB
  unsigned short* WpT   = (unsigned short*)(ws + (12u << 20));      //  2 MB
  float*          bias2 = (float*)         (ws + (14u << 20));      //  4 KB
  unsigned short* Qjl   = (unsigned short*)(ws + (15u << 20));      //  4 MB
  unsigned short* Kjl   = (unsigned short*)(ws + (19u << 20));      //  4 MB
  unsigned short* Vc    = (unsigned short*)(ws + (23u << 20));      //  8 MB
  unsigned short* AO    = (unsigned short*)(ws + (31u << 20));      //  8 MB

  prep_kernel<<<2688, 256, 0, stream>>>(hidden, hB, W_attn, b_attn, S_proj,
                                        W_proj, Bt2, WpT, bias2);
  qkv2_gemm_kernel<<<dim3(N2 / 128, (B_ * S_) / 128), 256, 0, stream>>>(
      hB, Bt2, b_attn, bias2, Qjl, Kjl, Vc);
  attn_kernel<<<512, 256, 0, stream>>>(Qjl, Kjl, Vc, AO);
  proj_gemm_kernel<<<dim3(D_ / 128, (B_ * S_) / 64), 256, 0, stream>>>(
      AO, WpT, b_proj, out);
}